// Round 5
// baseline (456.384 us; speedup 1.0000x reference)
//
#include <hip/hip_runtime.h>
#include <stdint.h>

#define N_SAMP 131072
#define DIN    256
#define HIDN   1024
#define BROWS  256           // rows per block, 64 per wave; 512 blocks
#define NTHREADS 256         // 4 waves/block; the ONLY config that gets >64 VGPRs
#define NCHUNK 16            // 16 chunks of 64 hidden cols

typedef __attribute__((ext_vector_type(8))) short short8;
typedef __attribute__((ext_vector_type(4))) float f32x4;

__device__ __forceinline__ unsigned short f2bf(float f) {
  unsigned u = __float_as_uint(f);
  u += 0x7fffu + ((u >> 16) & 1u);   // round-to-nearest-even (inputs finite)
  return (unsigned short)(u >> 16);
}

__device__ __forceinline__ short8 pack8(float4 a, float4 b) {
  short8 r;
  r[0] = (short)f2bf(a.x); r[1] = (short)f2bf(a.y);
  r[2] = (short)f2bf(a.z); r[3] = (short)f2bf(a.w);
  r[4] = (short)f2bf(b.x); r[5] = (short)f2bf(b.y);
  r[6] = (short)f2bf(b.z); r[7] = (short)f2bf(b.w);
  return r;
}

// Pre-convert W1 (fp32 [1024][256]) -> bf16 row-major in workspace (512 KB).
__global__ __launch_bounds__(256) void w1_to_bf16(const float* __restrict__ W1,
                                                  unsigned short* __restrict__ o) {
  int i = blockIdx.x * 256 + threadIdx.x;          // 65536 threads, 4 elems each
  float4 f = ((const float4*)W1)[i];
  ushort4 v;
  v.x = f2bf(f.x); v.y = f2bf(f.y); v.z = f2bf(f.z); v.w = f2bf(f.w);
  ((ushort4*)o)[i] = v;
}

// Fused: h = relu(x@W1^T + b1); y = dot(We[c[num]], h) + be[...]; out = sigmoid(y)
//
// Occupancy/arch history (rounds 0-4):
//  - r0: 256thr/(256,2): VGPR 124 no-spill, 2 waves/SIMD, 119us.
//  - r1/r3/r4: every spelling of "512thr at 4 waves/EU" (launch_bounds(512,4),
//    waves_per_eu(4), waves_per_eu(4,4)) clamps VGPR to 64 -> ~380MB scratch
//    spill traffic -> 257us. Toolchain will not budget >64 regs for 512-thr.
//  - r2: 33KB LDS / 4 small blocks per CU feasible but occupancy stuck at 21%.
//  => occupancy is pinned at 2 waves/SIMD. Stop fighting it.
//
// r5 (this): halve the dominant pipe instead. r0 pipe budget per CU:
//   LDS-read 8192 x ~16cyc = 55us  >  MFMA 33us  >  VALU 26us.
// B-fragment LDS traffic ~ 1/(row-tiles per wave). Go t=2 -> t=4 (64 rows/wave,
// afr = 128 VGPRs): LDS reads/CU halve to 4096 (~27-33us), MFMA/LDS-read x2.
// To stay under the 256-reg budget of (256,2), each 64-col chunk is computed
// in two 32-col half-passes (acc live = 32 regs, not 64). Est ~230 regs.
// Watch: FETCH~72MB & WRITE~0.5MB (no spill), SQ_LDS_BANK_CONFLICT ~4.2M.
template <bool WBF>
__global__ __launch_bounds__(NTHREADS, 2) void fused_kernel(
    const float* __restrict__ x,
    const float* __restrict__ W1f,
    const unsigned short* __restrict__ W1b,
    const float* __restrict__ b1,
    const float* __restrict__ We,   // [100][1024]
    const float* __restrict__ be,   // [100]
    const int* __restrict__ num,    // [N]
    const int* __restrict__ c,      // [100]
    float* __restrict__ out)        // [N]
{
  __shared__ unsigned short Wt[2][64 * DIN];  // 2 x 32 KB
  __shared__ int e_sh[BROWS];                 // 1 KB

  const int tid  = threadIdx.x;
  const int lane = tid & 63;
  const int w    = tid >> 6;        // wave 0..3
  const int n    = lane & 15;       // MFMA m/n lane coord
  const int quad = lane >> 4;       // 0..3
  const int R0   = blockIdx.x * BROWS;

  if (tid < BROWS) e_sh[tid] = c[num[R0 + tid]];

  // ---- A fragments: 4 row-tiles x 8 k-steps, register-resident (128 VGPRs).
  // A[m=lane&15][k=quad*8+j]; k0 = s*32 + quad*8.
  short8 afr[4][8];
  {
    const float* xr0 = x + (size_t)(R0 + w * 64 + n) * DIN + quad * 8;
#pragma unroll
    for (int t = 0; t < 4; ++t) {
      const float* xr = xr0 + (size_t)t * 16 * DIN;
#pragma unroll
      for (int s = 0; s < 8; ++s) {
        float4 f0 = *(const float4*)(xr + s * 32);
        float4 f1 = *(const float4*)(xr + s * 32 + 4);
        afr[t][s] = pack8(f0, f1);
      }
    }
  }

  const int h2 = lane >> 5;   // staging: row-within-pair
  const int p  = lane & 31;   // staging: physical 16B slot in row

  // ---- stage chunk 0 into buf 0   (32 x 1KB instructions, 8 per wave)
  if (WBF) {
#pragma unroll
    for (int j = 0; j < 8; ++j) {
      int inst = w * 8 + j;                 // 0..31
      int r = inst * 2 + h2;                // 0..63
      int kg = p ^ ((r & 7) << 2);
      const unsigned short* g = W1b + (r << 8) + (kg << 3);
      __builtin_amdgcn_global_load_lds(
          (const __attribute__((address_space(1))) unsigned int*)g,
          (__attribute__((address_space(3))) unsigned int*)(&Wt[0][0] + inst * 512),
          16, 0, 0);
    }
  } else {
#pragma unroll
    for (int j = 0; j < 8; ++j) {
      int id = tid + j * NTHREADS;          // 0..2047
      int r = id >> 5, pp = id & 31;        // r 0..63
      int kg = pp ^ ((r & 7) << 2);
      const float* gs = W1f + (r << 8) + (kg << 3);
      float4 f0 = *(const float4*)gs;
      float4 f1 = *(const float4*)(gs + 4);
      *(short8*)&Wt[0][r * DIN + pp * 8] = pack8(f0, f1);
    }
  }

  __syncthreads();  // e_sh + chunk 0 ready

  int eoff[4][4];
#pragma unroll
  for (int t = 0; t < 4; ++t)
#pragma unroll
    for (int r = 0; r < 4; ++r)
      eoff[t][r] = e_sh[w * 64 + t * 16 + quad * 4 + r] * HIDN;

  float yacc[4][4];
#pragma unroll
  for (int t = 0; t < 4; ++t)
#pragma unroll
    for (int r = 0; r < 4; ++r) yacc[t][r] = 0.f;

  int buf = 0;
  for (int ch = 0; ch < NCHUNK; ++ch) {
    // ---- async-stage next chunk into the other buffer (lands during compute)
    if (ch + 1 < NCHUNK) {
      if (WBF) {
        const unsigned short* Wg = W1b + (size_t)(ch + 1) * (64 * DIN);
        unsigned short* db = &Wt[buf ^ 1][0];
#pragma unroll
        for (int j = 0; j < 8; ++j) {
          int inst = w * 8 + j;
          int r = inst * 2 + h2;
          int kg = p ^ ((r & 7) << 2);
          const unsigned short* g = Wg + (r << 8) + (kg << 3);
          __builtin_amdgcn_global_load_lds(
              (const __attribute__((address_space(1))) unsigned int*)g,
              (__attribute__((address_space(3))) unsigned int*)(db + inst * 512),
              16, 0, 0);
        }
      } else {
        const float* Wg = W1f + (size_t)(ch + 1) * (64 * DIN);
#pragma unroll
        for (int j = 0; j < 8; ++j) {
          int id = tid + j * NTHREADS;
          int r = id >> 5, pp = id & 31;
          int kg = pp ^ ((r & 7) << 2);
          const float* gs = Wg + (r << 8) + (kg << 3);
          float4 f0 = *(const float4*)gs;
          float4 f1 = *(const float4*)(gs + 4);
          *(short8*)&Wt[buf ^ 1][r * DIN + pp * 8] = pack8(f0, f1);
        }
      }
    }

    const unsigned short* WtB = &Wt[buf][0];

    // ---- two 32-col half-passes (keeps acc live at 32 regs, not 64)
#pragma unroll
    for (int half = 0; half < 2; ++half) {
      f32x4 acc[4][2];
#pragma unroll
      for (int t = 0; t < 4; ++t)
#pragma unroll
        for (int nn = 0; nn < 2; ++nn)
          acc[t][nn] = (f32x4){0.f, 0.f, 0.f, 0.f};

#pragma unroll
      for (int s = 0; s < 8; ++s) {
        const int F = (s * 4 + quad) ^ ((n & 7) << 2);  // swizzled 16B slot
        short8 bfr[2];
#pragma unroll
        for (int nn = 0; nn < 2; ++nn)
          bfr[nn] = *(const short8*)&WtB[((half * 2 + nn) * 16 + n) * DIN + F * 8];
#pragma unroll
        for (int t = 0; t < 4; ++t)
#pragma unroll
          for (int nn = 0; nn < 2; ++nn)
            acc[t][nn] = __builtin_amdgcn_mfma_f32_16x16x32_bf16(
                afr[t][s], bfr[nn], acc[t][nn], 0, 0, 0);
      }

      // ---- epilogue: +b1, relu, * gathered We row, accumulate y
      // C layout: col(n) = lane&15, row = quad*4 + reg  [m89/m91]
#pragma unroll
      for (int nn = 0; nn < 2; ++nn) {
        int col = ch * 64 + (half * 2 + nn) * 16 + n;
        float bv = b1[col];
        const float* Wec = We + col;
#pragma unroll
        for (int t = 0; t < 4; ++t)
#pragma unroll
          for (int r = 0; r < 4; ++r) {
            float h = acc[t][nn][r] + bv;
            h = fmaxf(h, 0.f);
            yacc[t][r] = fmaf(h, Wec[eoff[t][r]], yacc[t][r]);
          }
      }
    }

    __syncthreads();  // all reads of buf done; next-chunk staging drained
    buf ^= 1;
  }

  // ---- reduce partial y across the 16 n-lanes of each quad group
#pragma unroll
  for (int t = 0; t < 4; ++t)
#pragma unroll
    for (int r = 0; r < 4; ++r) {
      float v = yacc[t][r];
      v += __shfl_xor(v, 1);
      v += __shfl_xor(v, 2);
      v += __shfl_xor(v, 4);
      v += __shfl_xor(v, 8);
      yacc[t][r] = v;
    }

  if (n == 0) {
#pragma unroll
    for (int t = 0; t < 4; ++t)
#pragma unroll
      for (int r = 0; r < 4; ++r) {
        int row = R0 + w * 64 + t * 16 + quad * 4 + r;
        float yy = yacc[t][r] + be[eoff[t][r] >> 10];  // eoff / HIDN
        out[row] = 1.f / (1.f + __expf(-yy));
      }
  }
}

extern "C" void kernel_launch(void* const* d_in, const int* in_sizes, int n_in,
                              void* d_out, int out_size, void* d_ws, size_t ws_size,
                              hipStream_t stream) {
  const float* x   = (const float*)d_in[0];
  const float* W1  = (const float*)d_in[1];
  const float* b1  = (const float*)d_in[2];
  const float* We  = (const float*)d_in[3];
  const float* be  = (const float*)d_in[4];
  const int*   num = (const int*)d_in[5];
  const int*   c   = (const int*)d_in[6];
  float* out = (float*)d_out;

  const size_t w1bf_bytes = (size_t)HIDN * DIN * sizeof(unsigned short);
  const bool usebf = ws_size >= w1bf_bytes;
  unsigned short* w1bf = (unsigned short*)d_ws;

  if (usebf) {
    w1_to_bf16<<<dim3((HIDN * DIN / 4) / 256), dim3(256), 0, stream>>>(W1, w1bf);
    fused_kernel<true><<<dim3(N_SAMP / BROWS), dim3(NTHREADS), 0, stream>>>(
        x, W1, w1bf, b1, We, be, num, c, out);
  } else {
    fused_kernel<false><<<dim3(N_SAMP / BROWS), dim3(NTHREADS), 0, stream>>>(
        x, W1, w1bf, b1, We, be, num, c, out);
  }
}

// Round 6
// 306.279 us; speedup vs baseline: 1.4901x; 1.4901x over previous
//
#include <hip/hip_runtime.h>
#include <stdint.h>

#define N_SAMP 131072
#define DIN    256
#define HIDN   1024
#define BROWS  128           // rows per block, 32 per wave; 1024 blocks
#define NTHREADS 256         // 4 waves/block
#define NCHUNK 16            // 16 chunks of 64 hidden cols

typedef __attribute__((ext_vector_type(8))) short short8;
typedef __attribute__((ext_vector_type(4))) float f32x4;

__device__ __forceinline__ unsigned short f2bf(float f) {
  unsigned u = __float_as_uint(f);
  u += 0x7fffu + ((u >> 16) & 1u);   // round-to-nearest-even (inputs finite)
  return (unsigned short)(u >> 16);
}

__device__ __forceinline__ short8 pack8(float4 a, float4 b) {
  short8 r;
  r[0] = (short)f2bf(a.x); r[1] = (short)f2bf(a.y);
  r[2] = (short)f2bf(a.z); r[3] = (short)f2bf(a.w);
  r[4] = (short)f2bf(b.x); r[5] = (short)f2bf(b.y);
  r[6] = (short)f2bf(b.z); r[7] = (short)f2bf(b.w);
  return r;
}

// Pre-pack W1 (fp32 [1024][256]) into bf16 MFMA-fragment order (512 KB).
// Fragment index idx = ((ch*8 + s)*4 + nt)*64 + lane ; each frag = 16 B.
// Lane l of frag (ch,s,nt) holds W1[ch*64 + nt*16 + (l&15)][s*32 + (l>>4)*8 .. +8].
// => main-loop B-loads are PERFECTLY coalesced global_load_dwordx4 streams.
__global__ __launch_bounds__(256) void w1_pack(const float* __restrict__ W1,
                                               unsigned short* __restrict__ o) {
  int idx = blockIdx.x * 256 + threadIdx.x;   // 32768 frags
  int l  = idx & 63;
  int nt = (idx >> 6) & 3;
  int s  = (idx >> 8) & 7;
  int ch = idx >> 11;
  int col = ch * 64 + nt * 16 + (l & 15);
  int k0  = s * 32 + (l >> 4) * 8;
  const float* src = W1 + (size_t)col * DIN + k0;
  float4 f0 = *(const float4*)src;
  float4 f1 = *(const float4*)(src + 4);
  ((short8*)o)[idx] = pack8(f0, f1);
}

// Fused: h = relu(x@W1^T + b1); y = dot(We[c[num]], h) + be[...]; out = sigmoid(y)
//
// Architecture history (r0-r5):
//  - r0: LDS double-buffer staging, per-chunk __syncthreads: 119us. Counters:
//    MfmaUtil 24 / VALU 22 / LDS-pipe ~46% busy / HBM 8% -> NOTHING saturated;
//    loss is barrier-drain stall at 2 waves/SIMD.
//  - r1/r3/r4: every attempt to raise waves/SIMD clamps VGPR to 64 + spills.
//  - r5: t=4 (needs ~230 regs) -> clamped at 128 + spills. LAW: ~128 VGPR is
//    this toolchain's ceiling in every config. r0's 124 IS the ceiling.
//  => stop optimizing pipes/occupancy; remove the synchronization instead.
//
// r6 (this): W1 pre-packed in fragment order -> B-frags loaded DIRECTLY from
// L2 (W1=512KB, L2-resident) with coalesced dwordx4. No LDS for W1, no
// staging, ZERO barriers in the main loop. 1-step pipelined bfr[2][4]
// (statically unrolled -> registers). Reg budget ~ r0's proven 124.
// go/no-go: WRITE_SIZE <=1MB, VGPR <=130; LDS_BANK_CONFLICT -> ~0.
template <bool WBF>
__global__ __launch_bounds__(NTHREADS, 2) void fused_kernel(
    const float* __restrict__ x,
    const float* __restrict__ W1f,
    const unsigned short* __restrict__ W1p,  // packed fragments (WBF)
    const float* __restrict__ b1,
    const float* __restrict__ We,   // [100][1024]
    const float* __restrict__ be,   // [100]
    const int* __restrict__ num,    // [N]
    const int* __restrict__ c,      // [100]
    float* __restrict__ out)        // [N]
{
  __shared__ int e_sh[BROWS];       // ~512 B total LDS

  const int tid  = threadIdx.x;
  const int lane = tid & 63;
  const int w    = tid >> 6;        // wave 0..3
  const int n    = lane & 15;       // MFMA m/n lane coord
  const int quad = lane >> 4;       // 0..3
  const int R0   = blockIdx.x * BROWS;

  if (tid < BROWS) e_sh[tid] = c[num[R0 + tid]];

  // ---- A fragments: 2 row-tiles x 8 k-steps, register-resident (64 VGPRs).
  // A[m=lane&15][k=quad*8+j]; k0 = s*32 + quad*8.
  short8 afr[2][8];
  {
    const float* xr0 = x + (size_t)(R0 + w * 32 + n) * DIN + quad * 8;
#pragma unroll
    for (int t = 0; t < 2; ++t) {
      const float* xr = xr0 + (size_t)t * 16 * DIN;
#pragma unroll
      for (int s = 0; s < 8; ++s) {
        float4 f0 = *(const float4*)(xr + s * 32);
        float4 f1 = *(const float4*)(xr + s * 32 + 4);
        afr[t][s] = pack8(f0, f1);
      }
    }
  }

  __syncthreads();  // e_sh ready — the ONLY barrier in this kernel

  int eoff[2][4];
#pragma unroll
  for (int t = 0; t < 2; ++t)
#pragma unroll
    for (int r = 0; r < 4; ++r)
      eoff[t][r] = e_sh[w * 32 + t * 16 + quad * 4 + r] * HIDN;

  float yacc[2][4] = {{0.f, 0.f, 0.f, 0.f}, {0.f, 0.f, 0.f, 0.f}};

  const int lane8 = lane * 8;       // ushort offset of this lane's 16B frag

  for (int ch = 0; ch < NCHUNK; ++ch) {
    f32x4 acc[2][4];
#pragma unroll
    for (int t = 0; t < 2; ++t)
#pragma unroll
      for (int nt = 0; nt < 4; ++nt)
        acc[t][nt] = (f32x4){0.f, 0.f, 0.f, 0.f};

    if (WBF) {
      // packed: chunk base = ch*16384 ushorts; s stride 2048; nt stride 512
      const unsigned short* Wpc = W1p + (size_t)ch * 16384;
      short8 bfr[2][4];                       // statically indexed after unroll
      {
        const unsigned short* bp = Wpc + lane8;
#pragma unroll
        for (int nt = 0; nt < 4; ++nt)
          bfr[0][nt] = *(const short8*)(bp + nt * 512);
      }
#pragma unroll
      for (int s = 0; s < 8; ++s) {
        if (s + 1 < 8) {                      // prefetch next k-step's frags
          const unsigned short* bp = Wpc + (s + 1) * 2048 + lane8;
#pragma unroll
          for (int nt = 0; nt < 4; ++nt)
            bfr[(s + 1) & 1][nt] = *(const short8*)(bp + nt * 512);
        }
#pragma unroll
        for (int t = 0; t < 2; ++t)
#pragma unroll
          for (int nt = 0; nt < 4; ++nt)
            acc[t][nt] = __builtin_amdgcn_mfma_f32_16x16x32_bf16(
                afr[t][s], bfr[s & 1][nt], acc[t][nt], 0, 0, 0);
      }
    } else {
      // fallback: read fp32 W1 directly (uncoalesced but correct)
#pragma unroll
      for (int s = 0; s < 8; ++s) {
        short8 bfr[4];
#pragma unroll
        for (int nt = 0; nt < 4; ++nt) {
          int col = ch * 64 + nt * 16 + n;
          const float* gs = W1f + (size_t)col * DIN + s * 32 + quad * 8;
          float4 f0 = *(const float4*)gs;
          float4 f1 = *(const float4*)(gs + 4);
          bfr[nt] = pack8(f0, f1);
        }
#pragma unroll
        for (int t = 0; t < 2; ++t)
#pragma unroll
          for (int nt = 0; nt < 4; ++nt)
            acc[t][nt] = __builtin_amdgcn_mfma_f32_16x16x32_bf16(
                afr[t][s], bfr[nt], acc[t][nt], 0, 0, 0);
      }
    }

    // ---- epilogue: +b1, relu, * gathered We row, accumulate y
    // C layout: col(n) = lane&15, row = quad*4 + reg  [m89/m91]
#pragma unroll
    for (int nt = 0; nt < 4; ++nt) {
      int col = ch * 64 + nt * 16 + n;
      float bv = b1[col];
      const float* Wec = We + col;
#pragma unroll
      for (int t = 0; t < 2; ++t)
#pragma unroll
        for (int r = 0; r < 4; ++r) {
          float h = acc[t][nt][r] + bv;
          h = fmaxf(h, 0.f);
          yacc[t][r] = fmaf(h, Wec[eoff[t][r]], yacc[t][r]);
        }
    }
  }

  // ---- reduce partial y across the 16 n-lanes of each quad group
#pragma unroll
  for (int t = 0; t < 2; ++t)
#pragma unroll
    for (int r = 0; r < 4; ++r) {
      float v = yacc[t][r];
      v += __shfl_xor(v, 1);
      v += __shfl_xor(v, 2);
      v += __shfl_xor(v, 4);
      v += __shfl_xor(v, 8);
      yacc[t][r] = v;
    }

  if (n == 0) {
#pragma unroll
    for (int t = 0; t < 2; ++t)
#pragma unroll
      for (int r = 0; r < 4; ++r) {
        int row = R0 + w * 32 + t * 16 + quad * 4 + r;
        float yy = yacc[t][r] + be[eoff[t][r] >> 10];  // eoff / HIDN
        out[row] = 1.f / (1.f + __expf(-yy));
      }
  }
}

extern "C" void kernel_launch(void* const* d_in, const int* in_sizes, int n_in,
                              void* d_out, int out_size, void* d_ws, size_t ws_size,
                              hipStream_t stream) {
  const float* x   = (const float*)d_in[0];
  const float* W1  = (const float*)d_in[1];
  const float* b1  = (const float*)d_in[2];
  const float* We  = (const float*)d_in[3];
  const float* be  = (const float*)d_in[4];
  const int*   num = (const int*)d_in[5];
  const int*   c   = (const int*)d_in[6];
  float* out = (float*)d_out;

  const size_t w1p_bytes = (size_t)HIDN * DIN * sizeof(unsigned short);  // 512 KB
  const bool usebf = ws_size >= w1p_bytes;
  unsigned short* w1p = (unsigned short*)d_ws;

  if (usebf) {
    w1_pack<<<dim3((HIDN * DIN / 8) / 256), dim3(256), 0, stream>>>(W1, w1p);
    fused_kernel<true><<<dim3(N_SAMP / BROWS), dim3(NTHREADS), 0, stream>>>(
        x, W1, w1p, b1, We, be, num, c, out);
  } else {
    fused_kernel<false><<<dim3(N_SAMP / BROWS), dim3(NTHREADS), 0, stream>>>(
        x, W1, w1p, b1, We, be, num, c, out);
  }
}

// Round 7
// 261.405 us; speedup vs baseline: 1.7459x; 1.1717x over previous
//
#include <hip/hip_runtime.h>
#include <stdint.h>

#define N_SAMP 131072
#define DIN    256
#define HIDN   1024
#define BROWS  128           // rows per block, 32 per wave; 1024 blocks
#define NTHREADS 256         // 4 waves/block
#define NCHUNK 16            // 16 chunks of 64 hidden cols

typedef __attribute__((ext_vector_type(8))) short short8;
typedef __attribute__((ext_vector_type(4))) float f32x4;

__device__ __forceinline__ unsigned short f2bf(float f) {
  unsigned u = __float_as_uint(f);
  u += 0x7fffu + ((u >> 16) & 1u);   // round-to-nearest-even (inputs finite)
  return (unsigned short)(u >> 16);
}

__device__ __forceinline__ short8 pack8(float4 a, float4 b) {
  short8 r;
  r[0] = (short)f2bf(a.x); r[1] = (short)f2bf(a.y);
  r[2] = (short)f2bf(a.z); r[3] = (short)f2bf(a.w);
  r[4] = (short)f2bf(b.x); r[5] = (short)f2bf(b.y);
  r[6] = (short)f2bf(b.z); r[7] = (short)f2bf(b.w);
  return r;
}

// Pre-pack W1 (fp32 [1024][256]) into bf16 MFMA-fragment order (512 KB).
// Fragment index idx = ((ch*8 + s)*4 + nt)*64 + lane ; each frag = 16 B.
// Lane l of frag (ch,s,nt) holds W1[ch*64 + nt*16 + (l&15)][s*32 + (l>>4)*8 .. +8].
// Verified correct in r6 (absmax 0.0039, passed).
__global__ __launch_bounds__(256) void w1_pack(const float* __restrict__ W1,
                                               unsigned short* __restrict__ o) {
  int idx = blockIdx.x * 256 + threadIdx.x;   // 32768 frags
  int l  = idx & 63;
  int nt = (idx >> 6) & 3;
  int s  = (idx >> 8) & 7;
  int ch = idx >> 11;
  int col = ch * 64 + nt * 16 + (l & 15);
  int k0  = s * 32 + (l >> 4) * 8;
  const float* src = W1 + (size_t)col * DIN + k0;
  float4 f0 = *(const float4*)src;
  float4 f1 = *(const float4*)(src + 4);
  ((short8*)o)[idx] = pack8(f0, f1);
}

// Fused: h = relu(x@W1^T + b1); y = dot(We[c[num]], h) + be[...]; out = sigmoid(y)
//
// Architecture history (r0-r6):
//  - r0: LDS dbuf staging + per-chunk barrier, row-major+XOR-swizzle LDS:
//        119us, 8.39M bank conflicts, MfmaUtil 24.
//  - r1/r3/r4: all 512-thr occupancy spellings clamp VGPR to 64 -> spills.
//  - r2: smaller chunks -> more blocks/CU feasible but occupancy stuck; slower.
//  - r5: t=4 needs ~230 regs -> clamp at 128 + spills. ~128 VGPR is the law.
//  - r6: B-frags direct from L2 (packed W1), zero barriers: bank conflicts 0
//        and no spills, but 164us — L2 latency (~200-300cy) on the MFMA path
//        with only 1-step prefetch beats the barrier cost. LDS staging's
//        async global_load_lds + dbuf is the right latency absorber.
//
// r7 (this): r0's staging frame + r6's fragment-packed W1 in LDS:
//  - staging = linear contiguous 1KB spans (no swizzle; matches
//    global_load_lds's base+lane*16 dest exactly)
//  - ds_read_b128 = 64 consecutive 16B lanes -> conflict-free (r6 measured 0)
//  - B address = one base + compile-time immediate (max 64512 < 65536) ->
//    zero address VALU in the inner loop.
// Watch: SQ_LDS_BANK_CONFLICT -> ~0, VGPR <=124, FETCH ~72MB, WRITE ~0.5MB.
template <bool WBF>
__global__ __launch_bounds__(NTHREADS, 2) void fused_kernel(
    const float* __restrict__ x,
    const float* __restrict__ W1f,
    const unsigned short* __restrict__ W1p,  // packed fragments (WBF)
    const float* __restrict__ b1,
    const float* __restrict__ We,   // [100][1024]
    const float* __restrict__ be,   // [100]
    const int* __restrict__ num,    // [N]
    const int* __restrict__ c,      // [100]
    float* __restrict__ out)        // [N]
{
  __shared__ unsigned short Wt[2][16384];  // 2 x 32 KB, fragment order
  __shared__ int e_sh[BROWS];

  const int tid  = threadIdx.x;
  const int lane = tid & 63;
  const int w    = tid >> 6;        // wave 0..3
  const int n    = lane & 15;       // MFMA m/n lane coord
  const int quad = lane >> 4;       // 0..3
  const int R0   = blockIdx.x * BROWS;

  if (tid < BROWS) e_sh[tid] = c[num[R0 + tid]];

  // ---- A fragments: 2 row-tiles x 8 k-steps, register-resident (64 VGPRs).
  // A[m=lane&15][k=quad*8+j]; k0 = s*32 + quad*8.
  short8 afr[2][8];
  {
    const float* xr0 = x + (size_t)(R0 + w * 32 + n) * DIN + quad * 8;
#pragma unroll
    for (int t = 0; t < 2; ++t) {
      const float* xr = xr0 + (size_t)t * 16 * DIN;
#pragma unroll
      for (int s = 0; s < 8; ++s) {
        float4 f0 = *(const float4*)(xr + s * 32);
        float4 f1 = *(const float4*)(xr + s * 32 + 4);
        afr[t][s] = pack8(f0, f1);
      }
    }
  }

  // ---- stage chunk 0 into buf 0 (32 x 1KB linear spans, 8 per wave)
  if (WBF) {
#pragma unroll
    for (int j = 0; j < 8; ++j) {
      int inst = w * 8 + j;                 // 0..31
      const unsigned short* g = W1p + inst * 512 + lane * 8;
      __builtin_amdgcn_global_load_lds(
          (const __attribute__((address_space(1))) unsigned int*)g,
          (__attribute__((address_space(3))) unsigned int*)(&Wt[0][0] + inst * 512),
          16, 0, 0);
    }
  } else {
    // fallback: pack fp32 W1 into fragment-order LDS by hand
#pragma unroll
    for (int j = 0; j < 8; ++j) {
      int id = tid + j * NTHREADS;          // 0..2047 = frag*64 + lane
      int l = id & 63, f = id >> 6;         // f = s*4+nt within chunk 0
      int nt = f & 3, s = f >> 2;
      int col = nt * 16 + (l & 15);
      int k0  = s * 32 + (l >> 4) * 8;
      const float* gs = W1f + (size_t)col * DIN + k0;
      float4 f0 = *(const float4*)gs;
      float4 f1 = *(const float4*)(gs + 4);
      *(short8*)&Wt[0][f * 512 + l * 8] = pack8(f0, f1);
    }
  }

  __syncthreads();  // e_sh + chunk 0 ready

  int eoff[2][4];
#pragma unroll
  for (int t = 0; t < 2; ++t)
#pragma unroll
    for (int r = 0; r < 4; ++r)
      eoff[t][r] = e_sh[w * 32 + t * 16 + quad * 4 + r] * HIDN;

  float yacc[2][4] = {{0.f, 0.f, 0.f, 0.f}, {0.f, 0.f, 0.f, 0.f}};

  int buf = 0;
  for (int ch = 0; ch < NCHUNK; ++ch) {
    // ---- async-stage next chunk into the other buffer (lands during compute)
    if (ch + 1 < NCHUNK) {
      if (WBF) {
        const unsigned short* Wg = W1p + (size_t)(ch + 1) * 16384;
        unsigned short* db = &Wt[buf ^ 1][0];
#pragma unroll
        for (int j = 0; j < 8; ++j) {
          int inst = w * 8 + j;
          const unsigned short* g = Wg + inst * 512 + lane * 8;
          __builtin_amdgcn_global_load_lds(
              (const __attribute__((address_space(1))) unsigned int*)g,
              (__attribute__((address_space(3))) unsigned int*)(db + inst * 512),
              16, 0, 0);
        }
      } else {
        const float* Wc = W1f + (size_t)(ch + 1) * 64 * DIN;
#pragma unroll
        for (int j = 0; j < 8; ++j) {
          int id = tid + j * NTHREADS;
          int l = id & 63, f = id >> 6;
          int nt = f & 3, s = f >> 2;
          int col = nt * 16 + (l & 15);
          int k0  = s * 32 + (l >> 4) * 8;
          const float* gs = Wc + (size_t)col * DIN + k0;
          float4 f0 = *(const float4*)gs;
          float4 f1 = *(const float4*)(gs + 4);
          *(short8*)&Wt[buf ^ 1][f * 512 + l * 8] = pack8(f0, f1);
        }
      }
    }

    // ---- MFMA over this chunk: 2 row-tiles x 4 col-tiles, K=256
    // B-frag (s,nt) lives at byte offset (s*4+nt)*1024 + lane*16 — pure
    // base+immediate ds_read_b128, linear across lanes (conflict-free).
    const char* Bbase = (const char*)&Wt[buf][0] + lane * 16;
    f32x4 acc[2][4];
#pragma unroll
    for (int t = 0; t < 2; ++t)
#pragma unroll
      for (int nt = 0; nt < 4; ++nt)
        acc[t][nt] = (f32x4){0.f, 0.f, 0.f, 0.f};

#pragma unroll
    for (int s = 0; s < 8; ++s) {
      short8 bfr[4];
#pragma unroll
      for (int nt = 0; nt < 4; ++nt)
        bfr[nt] = *(const short8*)(Bbase + (s * 4 + nt) * 1024);
#pragma unroll
      for (int t = 0; t < 2; ++t)
#pragma unroll
        for (int nt = 0; nt < 4; ++nt)
          acc[t][nt] = __builtin_amdgcn_mfma_f32_16x16x32_bf16(
              afr[t][s], bfr[nt], acc[t][nt], 0, 0, 0);
    }

    // ---- epilogue: +b1, relu, * gathered We row, accumulate y
    // C layout: col(n) = lane&15, row = quad*4 + reg  [m89/m91]
#pragma unroll
    for (int nt = 0; nt < 4; ++nt) {
      int col = ch * 64 + nt * 16 + n;
      float bv = b1[col];
      const float* Wec = We + col;
#pragma unroll
      for (int t = 0; t < 2; ++t)
#pragma unroll
        for (int r = 0; r < 4; ++r) {
          float h = acc[t][nt][r] + bv;
          h = fmaxf(h, 0.f);
          yacc[t][r] = fmaf(h, Wec[eoff[t][r]], yacc[t][r]);
        }
    }

    __syncthreads();  // all reads of buf done; next-chunk staging drained
    buf ^= 1;
  }

  // ---- reduce partial y across the 16 n-lanes of each quad group
#pragma unroll
  for (int t = 0; t < 2; ++t)
#pragma unroll
    for (int r = 0; r < 4; ++r) {
      float v = yacc[t][r];
      v += __shfl_xor(v, 1);
      v += __shfl_xor(v, 2);
      v += __shfl_xor(v, 4);
      v += __shfl_xor(v, 8);
      yacc[t][r] = v;
    }

  if (n == 0) {
#pragma unroll
    for (int t = 0; t < 2; ++t)
#pragma unroll
      for (int r = 0; r < 4; ++r) {
        int row = R0 + w * 32 + t * 16 + quad * 4 + r;
        float yy = yacc[t][r] + be[eoff[t][r] >> 10];  // eoff / HIDN
        out[row] = 1.f / (1.f + __expf(-yy));
      }
  }
}

extern "C" void kernel_launch(void* const* d_in, const int* in_sizes, int n_in,
                              void* d_out, int out_size, void* d_ws, size_t ws_size,
                              hipStream_t stream) {
  const float* x   = (const float*)d_in[0];
  const float* W1  = (const float*)d_in[1];
  const float* b1  = (const float*)d_in[2];
  const float* We  = (const float*)d_in[3];
  const float* be  = (const float*)d_in[4];
  const int*   num = (const int*)d_in[5];
  const int*   c   = (const int*)d_in[6];
  float* out = (float*)d_out;

  const size_t w1p_bytes = (size_t)HIDN * DIN * sizeof(unsigned short);  // 512 KB
  const bool usebf = ws_size >= w1p_bytes;
  unsigned short* w1p = (unsigned short*)d_ws;

  if (usebf) {
    w1_pack<<<dim3((HIDN * DIN / 8) / 256), dim3(256), 0, stream>>>(W1, w1p);
    fused_kernel<true><<<dim3(N_SAMP / BROWS), dim3(NTHREADS), 0, stream>>>(
        x, W1, w1p, b1, We, be, num, c, out);
  } else {
    fused_kernel<false><<<dim3(N_SAMP / BROWS), dim3(NTHREADS), 0, stream>>>(
        x, W1, w1p, b1, We, be, num, c, out);
  }
}